// Round 1
// baseline (230.980 us; speedup 1.0000x reference)
//
#include <hip/hip_runtime.h>

// CosineHammingLSH bucketed attention-like op.
// B=4, H=16, N=4096, D=64, BUCKET=64 -> 64 blocks of 64 q-rows per (b,h).
// Per (b,h,blk): gather Q,K,W rows; S = Q K^T (64x64x64); A = exp(S);
// R = A W (64x64x64); scatter R rows to out[Q_sort_idx[n]].
// fp32 vector-ALU compute (no fp32 MFMA on CDNA4; bf16 cast unsafe through exp).

constexpr int Nc      = 4096;
constexpr int Dc      = 64;
constexpr int BUCKETc = 64;
constexpr int NBc     = Nc / BUCKETc;  // 64 blocks per (b,h)
constexpr int LD      = 68;            // padded LDS stride (floats): 16B-aligned float4, ~2-way banks

__global__ __launch_bounds__(256, 3)
void lsh_bucket_attn(const float* __restrict__ query,
                     const float* __restrict__ key,
                     const float* __restrict__ weight,
                     const int*   __restrict__ K_sort_idx,
                     const int*   __restrict__ Q_sort_idx,
                     float*       __restrict__ out)
{
    __shared__ __align__(16) float QsT[Dc][LD];      // Q^T (d-major); reused as A^T after GEMM1
    __shared__ __align__(16) float KsT[Dc][LD];      // K^T (d-major)
    __shared__ __align__(16) float Wsh[BUCKETc][LD]; // W natural (m-major)
    __shared__ int qpos[BUCKETc];

    const int wg  = blockIdx.x;       // 0..B*H*NB-1
    const int bh  = wg >> 6;          // / NBc
    const int blk = wg & (NBc - 1);
    const int t   = threadIdx.x;
    const int tc  = t & 15;           // 0..15: column group (16 threads cover a 64-float row)
    const int tr  = t >> 4;           // 0..15: row group

    const size_t rowbase = (size_t)bh * Nc;        // row index base into [BH][N][D]
    const int    idxbase = bh * Nc + blk * BUCKETc;

    // ---- gather-load: Q,K transposed into LDS; W natural; remember Q scatter positions ----
    #pragma unroll
    for (int p = 0; p < 4; ++p) {
        const int r  = (p << 4) + tr;              // 0..63
        const int qi = Q_sort_idx[idxbase + r];
        const int ki = K_sort_idx[idxbase + r];
        if (tc == 0) qpos[r] = qi;
        const int c4 = tc << 2;
        const float4 q4 = *(const float4*)(query  + (rowbase + qi) * Dc + c4);
        const float4 k4 = *(const float4*)(key    + (rowbase + ki) * Dc + c4);
        const float4 w4 = *(const float4*)(weight + (rowbase + ki) * Dc + c4);
        QsT[c4 + 0][r] = q4.x; QsT[c4 + 1][r] = q4.y;
        QsT[c4 + 2][r] = q4.z; QsT[c4 + 3][r] = q4.w;
        KsT[c4 + 0][r] = k4.x; KsT[c4 + 1][r] = k4.y;
        KsT[c4 + 2][r] = k4.z; KsT[c4 + 3][r] = k4.w;
        *(float4*)&Wsh[r][c4] = w4;
    }
    __syncthreads();

    const int tx = tc;  // output col tile (4 cols)
    const int ty = tr;  // output row tile (4 rows)

    // ---- GEMM1: S[n][m] = sum_d Q[n][d] * K[m][d] ----
    float s[4][4] = {};
    #pragma unroll 8
    for (int k = 0; k < Dc; ++k) {
        const float4 a4 = *(const float4*)&QsT[k][ty << 2];
        const float4 b4 = *(const float4*)&KsT[k][tx << 2];
        const float a[4] = {a4.x, a4.y, a4.z, a4.w};
        const float b[4] = {b4.x, b4.y, b4.z, b4.w};
        #pragma unroll
        for (int i = 0; i < 4; ++i)
            #pragma unroll
            for (int j = 0; j < 4; ++j)
                s[i][j] += a[i] * b[j];
    }
    __syncthreads();  // QsT reads done; safe to overwrite with A^T

    // ---- A = exp(S), stored transposed: AT[m][n] = exp(S[n][m]) into QsT ----
    #pragma unroll
    for (int i = 0; i < 4; ++i)
        #pragma unroll
        for (int j = 0; j < 4; ++j)
            QsT[(tx << 2) + j][(ty << 2) + i] = expf(s[i][j]);
    __syncthreads();

    // ---- GEMM2: R[n][v] = sum_m A[n][m] * W[m][v] ----
    float r[4][4] = {};
    #pragma unroll 8
    for (int k = 0; k < BUCKETc; ++k) {
        const float4 a4 = *(const float4*)&QsT[k][ty << 2];  // A^T
        const float4 b4 = *(const float4*)&Wsh[k][tx << 2];
        const float a[4] = {a4.x, a4.y, a4.z, a4.w};
        const float b[4] = {b4.x, b4.y, b4.z, b4.w};
        #pragma unroll
        for (int i = 0; i < 4; ++i)
            #pragma unroll
            for (int j = 0; j < 4; ++j)
                r[i][j] += a[i] * b[j];
    }

    // ---- scatter store: out[bh][qpos[n]][:] ----
    #pragma unroll
    for (int i = 0; i < 4; ++i) {
        const int n   = (ty << 2) + i;
        const int pos = qpos[n];
        const float4 o = {r[i][0], r[i][1], r[i][2], r[i][3]};
        *(float4*)(out + (rowbase + pos) * Dc + (tx << 2)) = o;
    }
}

extern "C" void kernel_launch(void* const* d_in, const int* in_sizes, int n_in,
                              void* d_out, int out_size, void* d_ws, size_t ws_size,
                              hipStream_t stream) {
    const float* query  = (const float*)d_in[0];
    const float* key    = (const float*)d_in[1];
    const float* weight = (const float*)d_in[2];
    const int*   kidx   = (const int*)d_in[3];
    const int*   qidx   = (const int*)d_in[4];
    float*       out    = (float*)d_out;

    const int BH = in_sizes[3] / Nc;               // 64
    const int grid = BH * NBc;                     // 4096 workgroups
    lsh_bucket_attn<<<grid, 256, 0, stream>>>(query, key, weight, kidx, qidx, out);
}

// Round 2
// 221.811 us; speedup vs baseline: 1.0413x; 1.0413x over previous
//
#include <hip/hip_runtime.h>

// CosineHammingLSH bucketed attention, MFMA bf16x3 (split hi/lo) version.
// B*H=64, N=4096, D=64, BUCKET=64 -> 4096 independent buckets.
// One wave (64 lanes) per bucket, mfma_f32_32x32x16_bf16, 2x2 tiles of 32x32.
// S = Qh*KhT + Qh*KlT + Ql*KhT  (~17-bit mantissa emulation of fp32 GEMM)
// A = exp(S) -> packed (hi|lo) u32 in LDS -> A-operand frags for GEMM2
// R = Ah*Wh + Ah*Wl + Al*Wh -> scatter rows by Q_sort_idx.
// No __syncthreads anywhere: each wave owns its LDS slice.

typedef __attribute__((ext_vector_type(8)))  short bf16x8;
typedef __attribute__((ext_vector_type(16))) float f32x16;

constexpr int Nc  = 4096;
constexpr int Dc  = 64;
constexpr int LDA = 66;   // dword stride of Apk rows (pad: writes 2-way, reads <=4-way)
constexpr int WPB = 3;    // waves (=buckets) per block; LDS 3*17408 = 52 KB

union FragU { uint u[4]; bf16x8 v; };

__device__ __forceinline__ uint bfh(float x) {            // fp32 -> bf16 bits (RNE)
    uint u = __float_as_uint(x);
    return (u + 0x7fffu + ((u >> 16) & 1u)) >> 16;
}
__device__ __forceinline__ float bf2f(uint h) { return __uint_as_float(h << 16); }

__device__ __forceinline__ void split2(float x0, float x1, uint& hp, uint& lp) {
    uint h0 = bfh(x0), h1 = bfh(x1);
    float r0 = x0 - bf2f(h0);
    float r1 = x1 - bf2f(h1);
    uint l0 = bfh(r0), l1 = bfh(r1);
    hp = h0 | (h1 << 16);
    lp = l0 | (l1 << 16);
}

#define MFMA32(A, B, C) __builtin_amdgcn_mfma_f32_32x32x16_bf16((A), (B), (C), 0, 0, 0)

__global__ __launch_bounds__(WPB * 64)
void lsh_mfma_kernel(const float* __restrict__ Qg, const float* __restrict__ Kg,
                     const float* __restrict__ Wg, const int* __restrict__ Kidx,
                     const int* __restrict__ Qidx, float* __restrict__ Og,
                     int nbuck)
{
    __shared__ uint Apk[WPB][64][LDA];
    __shared__ int  kposL[WPB][64];
    __shared__ int  qposL[WPB][64];

    const int wv   = threadIdx.x >> 6;
    const int lane = threadIdx.x & 63;
    const int bucket = blockIdx.x * WPB + wv;
    if (bucket >= nbuck) return;          // wave-uniform exit, no barriers used

    const int bh  = bucket >> 6;          // which (b,h)
    const int blk = bucket & 63;          // which bucket within (b,h)
    const size_t base = (size_t)bh * (size_t)(Nc * Dc);
    const int ib = bh * Nc + blk * 64;

    const int c32 = lane & 31;
    const int h   = lane >> 5;

    kposL[wv][lane] = Kidx[ib + lane];
    qposL[wv][lane] = Qidx[ib + lane];

    // ---------- Q fragments (A-operand): global gather -> split bf16 hi/lo ----------
    // A-frag layout (32x32x16): row = lane&31 (+32*ti), k = 8*(lane>>5) + e  (+16*ks)
    FragU qh[2][4], ql[2][4];             // [ti][ks], all indices compile-time
    #pragma unroll
    for (int ti = 0; ti < 2; ++ti) {
        const int qrow = qposL[wv][32 * ti + c32];
        const float* p = Qg + base + (size_t)qrow * Dc + 8 * h;
        #pragma unroll
        for (int ks = 0; ks < 4; ++ks) {
            const float4 a = *(const float4*)(p + 16 * ks);
            const float4 b = *(const float4*)(p + 16 * ks + 4);
            split2(a.x, a.y, qh[ti][ks].u[0], ql[ti][ks].u[0]);
            split2(a.z, a.w, qh[ti][ks].u[1], ql[ti][ks].u[1]);
            split2(b.x, b.y, qh[ti][ks].u[2], ql[ti][ks].u[2]);
            split2(b.z, b.w, qh[ti][ks].u[3], ql[ti][ks].u[3]);
        }
    }

    // ---------- GEMM1: S = Q * K^T (bf16x3) ----------
    f32x16 S00 = (f32x16)0.0f, S01 = (f32x16)0.0f;
    f32x16 S10 = (f32x16)0.0f, S11 = (f32x16)0.0f;

    #pragma unroll
    for (int tj = 0; tj < 2; ++tj) {
        FragU kh[4], kl[4];
        const int krow = kposL[wv][32 * tj + c32];
        const float* p = Kg + base + (size_t)krow * Dc + 8 * h;
        #pragma unroll
        for (int ks = 0; ks < 4; ++ks) {
            const float4 a = *(const float4*)(p + 16 * ks);
            const float4 b = *(const float4*)(p + 16 * ks + 4);
            split2(a.x, a.y, kh[ks].u[0], kl[ks].u[0]);
            split2(a.z, a.w, kh[ks].u[1], kl[ks].u[1]);
            split2(b.x, b.y, kh[ks].u[2], kl[ks].u[2]);
            split2(b.z, b.w, kh[ks].u[3], kl[ks].u[3]);
        }
        #pragma unroll
        for (int ks = 0; ks < 4; ++ks) {
            if (tj == 0) {
                S00 = MFMA32(qh[0][ks].v, kh[ks].v, S00);
                S00 = MFMA32(qh[0][ks].v, kl[ks].v, S00);
                S00 = MFMA32(ql[0][ks].v, kh[ks].v, S00);
                S10 = MFMA32(qh[1][ks].v, kh[ks].v, S10);
                S10 = MFMA32(qh[1][ks].v, kl[ks].v, S10);
                S10 = MFMA32(ql[1][ks].v, kh[ks].v, S10);
            } else {
                S01 = MFMA32(qh[0][ks].v, kh[ks].v, S01);
                S01 = MFMA32(qh[0][ks].v, kl[ks].v, S01);
                S01 = MFMA32(ql[0][ks].v, kh[ks].v, S01);
                S11 = MFMA32(qh[1][ks].v, kh[ks].v, S11);
                S11 = MFMA32(qh[1][ks].v, kl[ks].v, S11);
                S11 = MFMA32(ql[1][ks].v, kh[ks].v, S11);
            }
        }
    }

    // ---------- A = exp(S): pack (hi | lo<<16) u32 into LDS ----------
    // C/D layout (32x32): col = lane&31, row = (r&3) + 8*(r>>2) + 4*(lane>>5)
    #pragma unroll
    for (int r = 0; r < 16; ++r) {
        const int rb = 4 * h + (r & 3) + 8 * (r >> 2);
        const float a00 = __expf(S00[r]);
        const float a01 = __expf(S01[r]);
        const float a10 = __expf(S10[r]);
        const float a11 = __expf(S11[r]);
        const uint h00 = bfh(a00), l00 = bfh(a00 - bf2f(h00));
        const uint h01 = bfh(a01), l01 = bfh(a01 - bf2f(h01));
        const uint h10 = bfh(a10), l10 = bfh(a10 - bf2f(h10));
        const uint h11 = bfh(a11), l11 = bfh(a11 - bf2f(h11));
        Apk[wv][rb][c32]           = h00 | (l00 << 16);
        Apk[wv][rb][32 + c32]      = h01 | (l01 << 16);
        Apk[wv][32 + rb][c32]      = h10 | (l10 << 16);
        Apk[wv][32 + rb][32 + c32] = h11 | (l11 << 16);
    }

    // ---------- W fragments (B-operand): scalar gathered loads ----------
    // B-frag layout: col = lane&31 (+32*tj), k = 8*(lane>>5) + e (+16*ks)
    FragU wh[2][4], wl[2][4];             // [tj][ks]
    #pragma unroll
    for (int tj = 0; tj < 2; ++tj) {
        #pragma unroll
        for (int ks = 0; ks < 4; ++ks) {
            #pragma unroll
            for (int j = 0; j < 4; ++j) {
                const int m0 = 16 * ks + 8 * h + 2 * j;
                const int r0 = kposL[wv][m0];
                const int r1 = kposL[wv][m0 + 1];
                const float x0 = Wg[base + (size_t)r0 * Dc + 32 * tj + c32];
                const float x1 = Wg[base + (size_t)r1 * Dc + 32 * tj + c32];
                split2(x0, x1, wh[tj][ks].u[j], wl[tj][ks].u[j]);
            }
        }
    }

    // ---------- GEMM2: R = A * W (bf16x3), A-frags re-read from LDS ----------
    f32x16 R00 = (f32x16)0.0f, R01 = (f32x16)0.0f;
    f32x16 R10 = (f32x16)0.0f, R11 = (f32x16)0.0f;

    #pragma unroll
    for (int ti = 0; ti < 2; ++ti) {
        #pragma unroll
        for (int ks = 0; ks < 4; ++ks) {
            const uint* pr = &Apk[wv][32 * ti + c32][16 * ks + 8 * h];  // 8B-aligned
            const uint2 u0 = *(const uint2*)(pr + 0);
            const uint2 u1 = *(const uint2*)(pr + 2);
            const uint2 u2 = *(const uint2*)(pr + 4);
            const uint2 u3 = *(const uint2*)(pr + 6);
            FragU ah, al;
            ah.u[0] = (u0.x & 0xffffu) | (u0.y << 16);
            al.u[0] = (u0.x >> 16)     | (u0.y & 0xffff0000u);
            ah.u[1] = (u1.x & 0xffffu) | (u1.y << 16);
            al.u[1] = (u1.x >> 16)     | (u1.y & 0xffff0000u);
            ah.u[2] = (u2.x & 0xffffu) | (u2.y << 16);
            al.u[2] = (u2.x >> 16)     | (u2.y & 0xffff0000u);
            ah.u[3] = (u3.x & 0xffffu) | (u3.y << 16);
            al.u[3] = (u3.x >> 16)     | (u3.y & 0xffff0000u);
            if (ti == 0) {
                R00 = MFMA32(ah.v, wh[0][ks].v, R00);
                R00 = MFMA32(ah.v, wl[0][ks].v, R00);
                R00 = MFMA32(al.v, wh[0][ks].v, R00);
                R01 = MFMA32(ah.v, wh[1][ks].v, R01);
                R01 = MFMA32(ah.v, wl[1][ks].v, R01);
                R01 = MFMA32(al.v, wh[1][ks].v, R01);
            } else {
                R10 = MFMA32(ah.v, wh[0][ks].v, R10);
                R10 = MFMA32(ah.v, wl[0][ks].v, R10);
                R10 = MFMA32(al.v, wh[0][ks].v, R10);
                R11 = MFMA32(ah.v, wh[1][ks].v, R11);
                R11 = MFMA32(ah.v, wl[1][ks].v, R11);
                R11 = MFMA32(al.v, wh[1][ks].v, R11);
            }
        }
    }

    // ---------- scatter store rows by Q_sort_idx ----------
    #pragma unroll
    for (int ti = 0; ti < 2; ++ti) {
        #pragma unroll
        for (int r = 0; r < 16; ++r) {
            const int row  = 32 * ti + 4 * h + (r & 3) + 8 * (r >> 2);
            const int orow = qposL[wv][row];
            float* po = Og + base + (size_t)orow * Dc;
            po[c32]      = (ti == 0) ? R00[r] : R10[r];
            po[32 + c32] = (ti == 0) ? R01[r] : R11[r];
        }
    }
}

extern "C" void kernel_launch(void* const* d_in, const int* in_sizes, int n_in,
                              void* d_out, int out_size, void* d_ws, size_t ws_size,
                              hipStream_t stream) {
    const float* query  = (const float*)d_in[0];
    const float* key    = (const float*)d_in[1];
    const float* weight = (const float*)d_in[2];
    const int*   kidx   = (const int*)d_in[3];
    const int*   qidx   = (const int*)d_in[4];
    float*       out    = (float*)d_out;

    const int BH    = in_sizes[3] / Nc;        // 64
    const int nbuck = BH * (Nc / 64);          // 4096 buckets
    const int blocks = (nbuck + WPB - 1) / WPB;
    lsh_mfma_kernel<<<blocks, WPB * 64, 0, stream>>>(query, key, weight, kidx, qidx, out, nbuck);
}